// Round 3
// baseline (405.208 us; speedup 1.0000x reference)
//
#include <hip/hip_runtime.h>
#include <hip/hip_bf16.h>
#include <math.h>

#define BB 16
#define NTOK 1024
#define CDIM 256
#define HEADS 8
#define HD 32

typedef __attribute__((ext_vector_type(8))) __bf16 bf16x8;
typedef __attribute__((ext_vector_type(8))) unsigned short u16x8;
typedef __attribute__((ext_vector_type(4))) float f32x4;

// Split fp32 into bf16 hi (truncation) + bf16 lo (truncation of residual).
__device__ __forceinline__ void split_bf(float f, unsigned short& hi,
                                         unsigned short& lo) {
  unsigned u = __float_as_uint(f);
  hi = (unsigned short)(u >> 16);
  float fl = f - __uint_as_float(u & 0xFFFF0000u);
  lo = (unsigned short)(__float_as_uint(fl) >> 16);
}

__device__ __forceinline__ bf16x8 ldb8(const unsigned short* p) {
  return *reinterpret_cast<const bf16x8*>(p);
}

// ---------------------------------------------------------------------------
// Split X (16384x256 fp32) into bf16 hi/lo, 8 elems/thread.
// ---------------------------------------------------------------------------
__global__ __launch_bounds__(256) void split_x(const float* __restrict__ X,
                                               unsigned short* __restrict__ xhi,
                                               unsigned short* __restrict__ xlo) {
  size_t base = ((size_t)blockIdx.x * 256 + threadIdx.x) * 8;
  float4 a = *(const float4*)(X + base);
  float4 b = *(const float4*)(X + base + 4);
  float v[8] = {a.x, a.y, a.z, a.w, b.x, b.y, b.z, b.w};
  u16x8 h, l;
#pragma unroll
  for (int j = 0; j < 8; ++j) {
    unsigned short hh, ll;
    split_bf(v[j], hh, ll);
    h[j] = hh; l[j] = ll;
  }
  *(u16x8*)(xhi + base) = h;
  *(u16x8*)(xlo + base) = l;
}

// ---------------------------------------------------------------------------
// Split + transpose weights: Wq(256,256)+Wkv(256,512) -> wt768(768,256) hi/lo,
// Wp(256,256) -> wpt(256,256) hi/lo.  (N,K) layout so B-fragments are 16B.
// ---------------------------------------------------------------------------
__global__ __launch_bounds__(256) void split_w(
    const float* __restrict__ Wq, const float* __restrict__ Wkv,
    const float* __restrict__ Wp, unsigned short* __restrict__ wthi,
    unsigned short* __restrict__ wtlo, unsigned short* __restrict__ wpthi,
    unsigned short* __restrict__ wptlo) {
  int idx = blockIdx.x * 256 + threadIdx.x;  // 0 .. 262143
  float val; size_t dst; bool isp = false;
  if (idx < 65536) {               // Wq: (k,n)
    int k = idx >> 8, n = idx & 255;
    val = Wq[idx]; dst = (size_t)n * 256 + k;
  } else if (idx < 196608) {       // Wkv: (k,n2) -> cols 256..767
    int i2 = idx - 65536;
    int k = i2 >> 9, n2 = i2 & 511;
    val = Wkv[i2]; dst = (size_t)(256 + n2) * 256 + k;
  } else {                         // Wp
    int i3 = idx - 196608;
    int k = i3 >> 8, n = i3 & 255;
    val = Wp[i3]; dst = (size_t)n * 256 + k; isp = true;
  }
  unsigned short h, l;
  split_bf(val, h, l);
  if (isp) { wpthi[dst] = h; wptlo[dst] = l; }
  else     { wthi[dst] = h; wtlo[dst] = l; }
}

// ---------------------------------------------------------------------------
// Per-query angle bias
// ---------------------------------------------------------------------------
__global__ __launch_bounds__(256) void bias_kernel(
    const float* __restrict__ affine, const float* __restrict__ atab,
    float* __restrict__ bias) {
  int idx = blockIdx.x * 256 + threadIdx.x;
  if (idx >= BB * NTOK) return;
  int b = idx >> 10, n = idx & (NTOK - 1);
  float cx = (float)(n & 31);
  float cy = (float)(n >> 5);
  const float* A = affine + b * 6;
  float egx = fmaf(A[0], 16.f, fmaf(A[1], 16.f, A[2]));
  float egy = fmaf(A[3], 16.f, fmaf(A[4], 16.f, A[5]));
  float ang = atan2f(cy - egy, cx - egx);
  float t = (ang + 3.14159265358979323846f) *
            (1.f / (2.f * 3.14159265358979323846f)) * 4.f;
  int bin = (int)t;
  bin = bin < 0 ? 0 : (bin > 4 ? 4 : bin);
  for (int h = 0; h < HEADS; ++h) {
    float a = atab[bin * HEADS + h];
    float s = 1.f / (1.f + __expf(-a));
    bias[((size_t)b * HEADS + h) * NTOK + n] = 1.f + s;
  }
}

// ---------------------------------------------------------------------------
// QKV projection, split-bf16 MFMA, no LDS. Block = 64 rows x 64 cols of the
// (16384 x 768) output; 4 waves, wave w owns rows m0+16w..+15, all 64 cols.
// Epilogue: +bias, (q: *scale*angle_bias), split, scatter to (B,h,N,d) /
// V transposed (B,h,d,N).
// ---------------------------------------------------------------------------
__global__ __launch_bounds__(256) void gemm_qkv_mfma(
    const unsigned short* __restrict__ xhi, const unsigned short* __restrict__ xlo,
    const unsigned short* __restrict__ wthi, const unsigned short* __restrict__ wtlo,
    const float* __restrict__ bq, const float* __restrict__ bkv,
    const float* __restrict__ bias,
    unsigned short* __restrict__ qhi, unsigned short* __restrict__ qlo,
    unsigned short* __restrict__ khi, unsigned short* __restrict__ klo,
    unsigned short* __restrict__ vthi, unsigned short* __restrict__ vtlo) {
  int tid = threadIdx.x;
  int w = tid >> 6, l = tid & 63;
  int row16 = l & 15, grp = l >> 4;
  int j0 = blockIdx.x * 64;
  int m0 = blockIdx.y * 64;
  const unsigned short* arh = xhi + ((size_t)(m0 + w * 16 + row16)) * CDIM;
  const unsigned short* arl = xlo + ((size_t)(m0 + w * 16 + row16)) * CDIM;
  f32x4 acc[4];
#pragma unroll
  for (int c = 0; c < 4; ++c) acc[c] = (f32x4){0.f, 0.f, 0.f, 0.f};
#pragma unroll
  for (int k0 = 0; k0 < CDIM; k0 += 32) {
    bf16x8 ah = ldb8(arh + k0 + grp * 8);
    bf16x8 al = ldb8(arl + k0 + grp * 8);
#pragma unroll
    for (int c = 0; c < 4; ++c) {
      size_t boff = ((size_t)(j0 + c * 16 + row16)) * CDIM + k0 + grp * 8;
      bf16x8 bh = ldb8(wthi + boff);
      bf16x8 bl = ldb8(wtlo + boff);
      acc[c] = __builtin_amdgcn_mfma_f32_16x16x32_bf16(ah, bh, acc[c], 0, 0, 0);
      acc[c] = __builtin_amdgcn_mfma_f32_16x16x32_bf16(al, bh, acc[c], 0, 0, 0);
      acc[c] = __builtin_amdgcn_mfma_f32_16x16x32_bf16(ah, bl, acc[c], 0, 0, 0);
    }
  }
  const float scale = 0.17677669529663687f;  // 32^-0.5
  int ng = m0 + w * 16 + grp * 4;
#pragma unroll
  for (int c = 0; c < 4; ++c) {
    int jg = j0 + c * 16 + row16;
#pragma unroll
    for (int r = 0; r < 4; ++r) {
      int m = ng + r;
      int b = m >> 10, n = m & (NTOK - 1);
      float val = acc[c][r];
      unsigned short hi, lo;
      if (jg < CDIM) {
        int h = jg >> 5, d = jg & 31;
        size_t idx = (((size_t)b * HEADS + h) * NTOK + n) * HD + d;
        float s = (val + bq[jg]) * scale * bias[((size_t)b * HEADS + h) * NTOK + n];
        split_bf(s, hi, lo);
        qhi[idx] = hi; qlo[idx] = lo;
      } else {
        int c2 = jg - CDIM;
        float vv = val + bkv[c2];
        if (c2 < CDIM) {
          int h = c2 >> 5, d = c2 & 31;
          size_t idx = (((size_t)b * HEADS + h) * NTOK + n) * HD + d;
          split_bf(vv, hi, lo);
          khi[idx] = hi; klo[idx] = lo;
        } else {
          int c3 = c2 - CDIM;
          int h = c3 >> 5, d = c3 & 31;
          size_t idxT = (((size_t)b * HEADS + h) * HD + d) * NTOK + n;
          split_bf(vv, hi, lo);
          vthi[idxT] = hi; vtlo[idxT] = lo;
        }
      }
    }
  }
}

// ---------------------------------------------------------------------------
// MFMA flash attention (split-bf16, wave-local, no __syncthreads).
// Epilogue writes aout pre-split into bf16 hi/lo for the output GEMM.
// ---------------------------------------------------------------------------
__global__ __launch_bounds__(256) void attn_mfma(
    const unsigned short* __restrict__ qhi, const unsigned short* __restrict__ qlo,
    const unsigned short* __restrict__ khi, const unsigned short* __restrict__ klo,
    const unsigned short* __restrict__ vthi, const unsigned short* __restrict__ vtlo,
    const float* __restrict__ mask, unsigned short* __restrict__ aohi,
    unsigned short* __restrict__ aolo) {
  __shared__ __align__(16) float Ps[64][68];
  int tid = threadIdx.x;
  int w = tid >> 6;
  int l = tid & 63;
  int row16 = l & 15;
  int grp = l >> 4;
  int qt = blockIdx.x, h = blockIdx.y, b = blockIdx.z;
  int q0 = qt * 64;
  int bh = b * HEADS + h;

  size_t qidx = (((size_t)bh * NTOK) + q0 + w * 16 + row16) * HD + grp * 8;
  bf16x8 aqh = ldb8(qhi + qidx);
  bf16x8 aql = ldb8(qlo + qidx);

  const unsigned short* kbase_hi = khi + (size_t)bh * NTOK * HD;
  const unsigned short* kbase_lo = klo + (size_t)bh * NTOK * HD;
  const unsigned short* vbase_hi = vthi + (size_t)bh * HD * NTOK;
  const unsigned short* vbase_lo = vtlo + (size_t)bh * HD * NTOK;
  const float* mrow = mask + (size_t)(b & 3) * NTOK * NTOK +
                      (size_t)(q0 + w * 16 + grp * 4) * NTOK + row16;

  f32x4 accd[2];
  accd[0] = (f32x4){0.f, 0.f, 0.f, 0.f};
  accd[1] = (f32x4){0.f, 0.f, 0.f, 0.f};
  float mst[4] = {-INFINITY, -INFINITY, -INFINITY, -INFINITY};
  float lst[4] = {0.f, 0.f, 0.f, 0.f};
  const f32x4 zero4 = (f32x4){0.f, 0.f, 0.f, 0.f};

  for (int kt = 0; kt < 16; ++kt) {
    int k0 = kt * 64;
    f32x4 s[4];
#pragma unroll
    for (int f = 0; f < 4; ++f) {
      size_t kidx = ((size_t)(k0 + f * 16 + row16)) * HD + grp * 8;
      bf16x8 kh = ldb8(kbase_hi + kidx);
      bf16x8 kl2 = ldb8(kbase_lo + kidx);
      f32x4 t = __builtin_amdgcn_mfma_f32_16x16x32_bf16(aqh, kh, zero4, 0, 0, 0);
      t = __builtin_amdgcn_mfma_f32_16x16x32_bf16(aql, kh, t, 0, 0, 0);
      t = __builtin_amdgcn_mfma_f32_16x16x32_bf16(aqh, kl2, t, 0, 0, 0);
      s[f] = t;
    }
#pragma unroll
    for (int r = 0; r < 4; ++r) {
      float s0 = s[0][r] + mrow[(size_t)r * NTOK + k0];
      float s1 = s[1][r] + mrow[(size_t)r * NTOK + k0 + 16];
      float s2 = s[2][r] + mrow[(size_t)r * NTOK + k0 + 32];
      float s3 = s[3][r] + mrow[(size_t)r * NTOK + k0 + 48];
      float mx = fmaxf(fmaxf(s0, s1), fmaxf(s2, s3));
#pragma unroll
      for (int off = 1; off < 16; off <<= 1)
        mx = fmaxf(mx, __shfl_xor(mx, off, 16));
      // defer-max (T13): only rescale when tile max exceeds running max + 8
      if (!__all(mx <= mst[r] + 8.f)) {
        float mnew = fmaxf(mst[r], mx);
        float corr = __expf(mst[r] - mnew);
        mst[r] = mnew;
        lst[r] *= corr;
        accd[0][r] *= corr;
        accd[1][r] *= corr;
      }
      float p0 = __expf(s0 - mst[r]), p1 = __expf(s1 - mst[r]);
      float p2 = __expf(s2 - mst[r]), p3 = __expf(s3 - mst[r]);
      float rs = (p0 + p1) + (p2 + p3);
#pragma unroll
      for (int off = 1; off < 16; off <<= 1)
        rs += __shfl_xor(rs, off, 16);
      lst[r] += rs;
      int prow = w * 16 + grp * 4 + r;
      Ps[prow][row16] = p0;
      Ps[prow][row16 + 16] = p1;
      Ps[prow][row16 + 32] = p2;
      Ps[prow][row16 + 48] = p3;
    }
#pragma unroll
    for (int ks = 0; ks < 2; ++ks) {
      const float* prow = &Ps[w * 16 + row16][ks * 32 + grp * 8];
      float4 pa = *reinterpret_cast<const float4*>(prow);
      float4 pb = *reinterpret_cast<const float4*>(prow + 4);
      u16x8 hu, lu;
      float pv[8] = {pa.x, pa.y, pa.z, pa.w, pb.x, pb.y, pb.z, pb.w};
#pragma unroll
      for (int j = 0; j < 8; ++j) {
        unsigned short hh, ll;
        split_bf(pv[j], hh, ll);
        hu[j] = hh; lu[j] = ll;
      }
      bf16x8 phi = __builtin_bit_cast(bf16x8, hu);
      bf16x8 plo = __builtin_bit_cast(bf16x8, lu);
#pragma unroll
      for (int df = 0; df < 2; ++df) {
        size_t vidx = ((size_t)(df * 16 + row16)) * NTOK + k0 + ks * 32 + grp * 8;
        bf16x8 vh = ldb8(vbase_hi + vidx);
        bf16x8 vl = ldb8(vbase_lo + vidx);
        accd[df] = __builtin_amdgcn_mfma_f32_16x16x32_bf16(phi, vh, accd[df], 0, 0, 0);
        accd[df] = __builtin_amdgcn_mfma_f32_16x16x32_bf16(plo, vh, accd[df], 0, 0, 0);
        accd[df] = __builtin_amdgcn_mfma_f32_16x16x32_bf16(phi, vl, accd[df], 0, 0, 0);
      }
    }
  }
#pragma unroll
  for (int r = 0; r < 4; ++r) {
    float inv = 1.f / lst[r];
    int qrow = q0 + w * 16 + grp * 4 + r;
    size_t obase = ((size_t)b * NTOK + qrow) * CDIM + h * HD;
    float v0 = accd[0][r] * inv, v1 = accd[1][r] * inv;
    unsigned short h0, l0, h1, l1;
    split_bf(v0, h0, l0);
    split_bf(v1, h1, l1);
    aohi[obase + row16] = h0; aolo[obase + row16] = l0;
    aohi[obase + 16 + row16] = h1; aolo[obase + 16 + row16] = l1;
  }
}

// ---------------------------------------------------------------------------
// Output projection, split-bf16 MFMA, no LDS: (16384x256) @ Wp + bp -> fp32.
// ---------------------------------------------------------------------------
__global__ __launch_bounds__(256) void gemm_out_mfma(
    const unsigned short* __restrict__ ahi, const unsigned short* __restrict__ alo,
    const unsigned short* __restrict__ wpthi, const unsigned short* __restrict__ wptlo,
    const float* __restrict__ bp, float* __restrict__ out) {
  int tid = threadIdx.x;
  int w = tid >> 6, l = tid & 63;
  int row16 = l & 15, grp = l >> 4;
  int j0 = blockIdx.x * 64;
  int m0 = blockIdx.y * 64;
  const unsigned short* arh = ahi + ((size_t)(m0 + w * 16 + row16)) * CDIM;
  const unsigned short* arl = alo + ((size_t)(m0 + w * 16 + row16)) * CDIM;
  f32x4 acc[4];
#pragma unroll
  for (int c = 0; c < 4; ++c) acc[c] = (f32x4){0.f, 0.f, 0.f, 0.f};
#pragma unroll
  for (int k0 = 0; k0 < CDIM; k0 += 32) {
    bf16x8 ah = ldb8(arh + k0 + grp * 8);
    bf16x8 al = ldb8(arl + k0 + grp * 8);
#pragma unroll
    for (int c = 0; c < 4; ++c) {
      size_t boff = ((size_t)(j0 + c * 16 + row16)) * CDIM + k0 + grp * 8;
      bf16x8 bh = ldb8(wpthi + boff);
      bf16x8 bl = ldb8(wptlo + boff);
      acc[c] = __builtin_amdgcn_mfma_f32_16x16x32_bf16(ah, bh, acc[c], 0, 0, 0);
      acc[c] = __builtin_amdgcn_mfma_f32_16x16x32_bf16(al, bh, acc[c], 0, 0, 0);
      acc[c] = __builtin_amdgcn_mfma_f32_16x16x32_bf16(ah, bl, acc[c], 0, 0, 0);
    }
  }
  int ng = m0 + w * 16 + grp * 4;
#pragma unroll
  for (int c = 0; c < 4; ++c) {
    int jg = j0 + c * 16 + row16;
    float bias = bp[jg];
#pragma unroll
    for (int r = 0; r < 4; ++r) {
      out[(size_t)(ng + r) * CDIM + jg] = acc[c][r] + bias;
    }
  }
}

// ---------------------------------------------------------------------------
extern "C" void kernel_launch(void* const* d_in, const int* in_sizes, int n_in,
                              void* d_out, int out_size, void* d_ws,
                              size_t ws_size, hipStream_t stream) {
  const float* x = (const float*)d_in[0];
  const float* mask = (const float*)d_in[1];
  const float* affine = (const float*)d_in[2];
  const float* Wq = (const float*)d_in[3];
  const float* bq = (const float*)d_in[4];
  const float* Wkv = (const float*)d_in[5];
  const float* bkv = (const float*)d_in[6];
  const float* Wp = (const float*)d_in[7];
  const float* bp = (const float*)d_in[8];
  const float* atab = (const float*)d_in[9];
  float* out = (float*)d_out;

  const size_t bhnd = (size_t)BB * HEADS * NTOK * HD;  // 4,194,304
  unsigned short* qhi = (unsigned short*)d_ws;
  unsigned short* qlo = qhi + bhnd;
  unsigned short* khi = qlo + bhnd;
  unsigned short* klo = khi + bhnd;
  unsigned short* vthi = klo + bhnd;
  unsigned short* vtlo = vthi + bhnd;
  unsigned short* xhi = vtlo + bhnd;   // aliased as aout_hi after qkv
  unsigned short* xlo = xhi + bhnd;    // aliased as aout_lo after qkv
  unsigned short* wthi = xlo + bhnd;             // 768*256
  unsigned short* wtlo = wthi + 768 * 256;
  unsigned short* wpthi = wtlo + 768 * 256;      // 256*256
  unsigned short* wptlo = wpthi + 256 * 256;
  float* bias = (float*)(wptlo + 256 * 256);

  split_x<<<2048, 256, 0, stream>>>(x, xhi, xlo);
  split_w<<<1024, 256, 0, stream>>>(Wq, Wkv, Wp, wthi, wtlo, wpthi, wptlo);
  bias_kernel<<<64, 256, 0, stream>>>(affine, atab, bias);
  gemm_qkv_mfma<<<dim3(12, 256), 256, 0, stream>>>(
      xhi, xlo, wthi, wtlo, bq, bkv, bias, qhi, qlo, khi, klo, vthi, vtlo);
  attn_mfma<<<dim3(16, 8, 16), 256, 0, stream>>>(qhi, qlo, khi, klo, vthi,
                                                 vtlo, mask, xhi, xlo);
  gemm_out_mfma<<<dim3(4, 256), 256, 0, stream>>>(xhi, xlo, wpthi, wptlo, bp,
                                                  out);
}